// Round 10
// baseline (376.974 us; speedup 1.0000x reference)
//
#include <hip/hip_runtime.h>
#include <math.h>

#define N_NODES   50000
#define N_EDGES   800000
#define IN_FEAT   64
#define HIDDEN    32
#define GRID_SZ   4
#define N_GRAPHS  128
#define NEG_SLOPE 0.01f
#define SCAN_BLOCKS 196   // ceil(50000/256)

// ---------------------------------------------------------------------------
__global__ __launch_bounds__(256) void zero_int_kernel(int* __restrict__ p, int n) {
  const int i = blockIdx.x * 256 + threadIdx.x;
  if (i < n) p[i] = 0;
}
__global__ __launch_bounds__(256) void zero_kernel(float* __restrict__ p, int n) {
  const int i = blockIdx.x * 256 + threadIdx.x;
  if (i < n) p[i] = 0.f;
}

// ---------------------------------------------------------------------------
// CSR build: histogram of dst into deg[]
// ---------------------------------------------------------------------------
__global__ __launch_bounds__(256) void hist_kernel(
    const int* __restrict__ dst, int* __restrict__ deg) {
  const int e = blockIdx.x * 256 + threadIdx.x;
  if (e < N_EDGES) atomicAdd(&deg[dst[e]], 1);
}

// multi-block scan, step A: per-block sums of deg -> bsum[SCAN_BLOCKS]
__global__ __launch_bounds__(256) void scanA_kernel(
    const int* __restrict__ deg, int* __restrict__ bsum) {
  const int i = blockIdx.x * 256 + threadIdx.x;
  int v = (i < N_NODES) ? deg[i] : 0;
#pragma unroll
  for (int o = 32; o > 0; o >>= 1) v += __shfl_down(v, o, 64);
  __shared__ int ws[4];
  if ((threadIdx.x & 63) == 0) ws[threadIdx.x >> 6] = v;
  __syncthreads();
  if (threadIdx.x == 0) bsum[blockIdx.x] = ws[0] + ws[1] + ws[2] + ws[3];
}

// step B: single small block scans the 196 block sums -> exclusive offsets
__global__ __launch_bounds__(256) void scanB_kernel(
    int* __restrict__ bsum, int* __restrict__ row_ptr) {
  __shared__ int sh[256];
  const int t = threadIdx.x;
  int v = (t < SCAN_BLOCKS) ? bsum[t] : 0;
  sh[t] = v;
  __syncthreads();
  for (int o = 1; o < 256; o <<= 1) {
    const int u = (t >= o) ? sh[t - o] : 0;
    __syncthreads();
    sh[t] += u;
    __syncthreads();
  }
  bsum[t] = (t == 0) ? 0 : sh[t - 1];   // exclusive
  if (t == 0) row_ptr[N_NODES] = N_EDGES;
}

// step C: per-block exclusive scan + block offset -> row_ptr, cursor
__global__ __launch_bounds__(256) void scanC_kernel(
    const int* __restrict__ deg, const int* __restrict__ bsum,
    int* __restrict__ row_ptr, int* __restrict__ cursor) {
  __shared__ int sh[256];
  const int t = threadIdx.x;
  const int i = blockIdx.x * 256 + t;
  const int v = (i < N_NODES) ? deg[i] : 0;
  sh[t] = v;
  __syncthreads();
  for (int o = 1; o < 256; o <<= 1) {
    const int u = (t >= o) ? sh[t - o] : 0;
    __syncthreads();
    sh[t] += u;
    __syncthreads();
  }
  if (i < N_NODES) {
    const int excl = bsum[blockIdx.x] + sh[t] - v;
    row_ptr[i] = excl;
    cursor[i] = excl;
  }
}

// fill: adj[pos] = src, pos = cursor[dst]++
__global__ __launch_bounds__(256) void fill_kernel(
    const int* __restrict__ src, const int* __restrict__ dst,
    int* __restrict__ cursor, int* __restrict__ adj) {
  const int e = blockIdx.x * 256 + threadIdx.x;
  if (e < N_EDGES) {
    const int pos = atomicAdd(&cursor[dst[e]], 1);
    adj[pos] = src[e];
  }
}

// ---------------------------------------------------------------------------
// gather + fused update: H[n] = leaky(H[n] + sum_{k in row(n)} T[adj[k]])
// ---------------------------------------------------------------------------
__global__ __launch_bounds__(256) void gather_update_kernel(
    const float* __restrict__ T, const int* __restrict__ row_ptr,
    const int* __restrict__ adj, float* __restrict__ H) {
  const int gid = blockIdx.x * 256 + threadIdx.x;
  const int n = gid >> 5;
  const int f = gid & 31;
  if (n >= N_NODES) return;
  const int lo = row_ptr[n], hi = row_ptr[n + 1];
  float acc = 0.f;
  for (int k = lo; k < hi; ++k) {
    const int s = adj[k];
    acc += T[s * HIDDEN + f];
  }
  float v = H[n * HIDDEN + f] + acc;
  v = (v >= 0.f) ? v : NEG_SLOPE * v;
  H[n * HIDDEN + f] = v;
}

// ---------------------------------------------------------------------------
// Input KAN v7: zero LDS. Wave = one o-octet (8 outputs), lanes = 64 nodes.
// Weight addresses depend only on (wave, i) -> readfirstlane forces SGPR base
// -> s_load broadcast on the scalar pipe; FMA = v_fmac acc, s_w, v_trig.
// Trig per-lane in-register: 1 sincosf + angle recurrence per i.
// ---------------------------------------------------------------------------
__global__ __launch_bounds__(256) void kan_input_v7(
    const float* __restrict__ X, const float* __restrict__ W,
    float* __restrict__ H) {
  const int lane = threadIdx.x & 63;
  const int octet = __builtin_amdgcn_readfirstlane(threadIdx.x >> 6);  // 0..3
  const int node = blockIdx.x * 64 + lane;
  const int ns = (node < N_NODES) ? node : (N_NODES - 1);
  const float* __restrict__ xr = X + ns * IN_FEAT;
  const float* __restrict__ w0 = W + octet * 8 * (IN_FEAT * GRID_SZ);
  const float* __restrict__ w1 = w0 + HIDDEN * IN_FEAT * GRID_SZ;  // +8192

  float acc[8];
#pragma unroll
  for (int oo = 0; oo < 8; ++oo) acc[oo] = 0.f;

  for (int i = 0; i < IN_FEAT; ++i) {
    const float v = xr[i];
    float s1, c1;
    sincosf(v, &s1, &c1);
    const float c2 = c1*c1 - s1*s1, s2 = s1*c1 + c1*s1;
    const float c3 = c2*c1 - s2*s1, s3 = s2*c1 + c2*s1;
    const float c4 = c3*c1 - s3*s1, s4 = s3*c1 + c3*s1;
#pragma unroll
    for (int oo = 0; oo < 8; ++oo) {
      const float4 a = *reinterpret_cast<const float4*>(w0 + oo * (IN_FEAT*GRID_SZ) + i * 4);
      const float4 b = *reinterpret_cast<const float4*>(w1 + oo * (IN_FEAT*GRID_SZ) + i * 4);
      acc[oo] += c1*a.x + c2*a.y + c3*a.z + c4*a.w
               + s1*b.x + s2*b.y + s3*b.z + s4*b.w;
    }
  }
  if (node < N_NODES) {
    float* __restrict__ hr = H + node * HIDDEN + octet * 8;
    *reinterpret_cast<float4*>(hr)     = make_float4(acc[0], acc[1], acc[2], acc[3]);
    *reinterpret_cast<float4*>(hr + 4) = make_float4(acc[4], acc[5], acc[6], acc[7]);
  }
}

// ---------------------------------------------------------------------------
// Conv KAN v7: same zero-LDS structure, 32 input feats.
// ---------------------------------------------------------------------------
__global__ __launch_bounds__(256) void kan_node_v7(
    const float* __restrict__ Hin, const float* __restrict__ W,
    float* __restrict__ T) {
  const int lane = threadIdx.x & 63;
  const int octet = __builtin_amdgcn_readfirstlane(threadIdx.x >> 6);  // 0..3
  const int node = blockIdx.x * 64 + lane;
  const int ns = (node < N_NODES) ? node : (N_NODES - 1);
  const float* __restrict__ w0 = W + octet * 8 * (HIDDEN * GRID_SZ);
  const float* __restrict__ w1 = w0 + HIDDEN * HIDDEN * GRID_SZ;  // +4096

  // preload own H row (32 floats)
  float hv[HIDDEN];
  const float4* __restrict__ hr4 = reinterpret_cast<const float4*>(Hin + ns * HIDDEN);
#pragma unroll
  for (int q = 0; q < HIDDEN / 4; ++q) {
    const float4 h4 = hr4[q];
    hv[q*4+0] = h4.x; hv[q*4+1] = h4.y; hv[q*4+2] = h4.z; hv[q*4+3] = h4.w;
  }

  float acc[8];
#pragma unroll
  for (int oo = 0; oo < 8; ++oo) acc[oo] = 0.f;

  for (int i = 0; i < HIDDEN; ++i) {
    const float v = hv[i];
    float s1, c1;
    sincosf(v, &s1, &c1);
    const float c2 = c1*c1 - s1*s1, s2 = s1*c1 + c1*s1;
    const float c3 = c2*c1 - s2*s1, s3 = s2*c1 + c2*s1;
    const float c4 = c3*c1 - s3*s1, s4 = s3*c1 + c3*s1;
#pragma unroll
    for (int oo = 0; oo < 8; ++oo) {
      const float4 a = *reinterpret_cast<const float4*>(w0 + oo * (HIDDEN*GRID_SZ) + i * 4);
      const float4 b = *reinterpret_cast<const float4*>(w1 + oo * (HIDDEN*GRID_SZ) + i * 4);
      acc[oo] += c1*a.x + c2*a.y + c3*a.z + c4*a.w
               + s1*b.x + s2*b.y + s3*b.z + s4*b.w;
    }
  }
  if (node < N_NODES) {
    float* __restrict__ tr = T + node * HIDDEN + octet * 8;
    *reinterpret_cast<float4*>(tr)     = make_float4(acc[0], acc[1], acc[2], acc[3]);
    *reinterpret_cast<float4*>(tr + 4) = make_float4(acc[4], acc[5], acc[6], acc[7]);
  }
}

// ---------------------------------------------------------------------------
// pool via run-length over sorted batch: thread = (range r, feat f)
// ---------------------------------------------------------------------------
#define POOL_RANGES 512
__global__ __launch_bounds__(256) void pool_rl(
    const float* __restrict__ H, const int* __restrict__ batch,
    float* __restrict__ sums, float* __restrict__ cnt) {
  const int tid = threadIdx.x;
  const int f = tid & 31;
  const int r = blockIdx.x * 8 + (tid >> 5);
  const int PER = (N_NODES + POOL_RANGES - 1) / POOL_RANGES;  // 98
  int n = r * PER;
  const int end = (n + PER < N_NODES) ? n + PER : N_NODES;
  if (n >= end) return;
  int g = batch[n];
  float acc = 0.f, c = 0.f;
  for (; n < end; ++n) {
    const int gn = batch[n];
    if (gn != g) {
      atomicAdd(&sums[g * HIDDEN + f], acc);
      if (f == 0) atomicAdd(&cnt[g], c);
      g = gn; acc = 0.f; c = 0.f;
    }
    acc += H[n * HIDDEN + f];
    c += 1.f;
  }
  atomicAdd(&sums[g * HIDDEN + f], acc);
  if (f == 0) atomicAdd(&cnt[g], c);
}

// ---------------------------------------------------------------------------
__global__ __launch_bounds__(128) void readout_kernel(
    const float* __restrict__ sums, const float* __restrict__ cnt,
    const float* __restrict__ Wout, const float* __restrict__ bout,
    float* __restrict__ out) {
  const int g = threadIdx.x;
  if (g < N_GRAPHS) {
    const float c = fmaxf(cnt[g], 1.0f);
    float z = 0.f;
#pragma unroll
    for (int i = 0; i < HIDDEN; ++i) {
      const float y = sums[g * HIDDEN + i] / c;
      z += cosf(y) * Wout[i] + sinf(y) * Wout[HIDDEN + i];
    }
    z += bout[0];
    out[g] = 1.0f / (1.0f + expf(-z));
  }
}

// ---------------------------------------------------------------------------
extern "C" void kernel_launch(void* const* d_in, const int* in_sizes, int n_in,
                              void* d_out, int out_size, void* d_ws, size_t ws_size,
                              hipStream_t stream) {
  const float* x        = (const float*)d_in[0];
  const int*   eidx     = (const int*)d_in[1];
  const int*   batch    = (const int*)d_in[2];
  const float* W_in     = (const float*)d_in[3];
  const float* W_conv   = (const float*)d_in[4];
  const float* W_out    = (const float*)d_in[5];
  const float* b_out    = (const float*)d_in[6];
  float* out            = (float*)d_out;

  const int* src = eidx;            // edge_index[0]
  const int* dst = eidx + N_EDGES;  // edge_index[1]

  float* ws = (float*)d_ws;
  float* H       = ws;                         // 1.6M floats
  float* T       = ws + 1600000;               // 1.6M floats
  int*   row_ptr = (int*)(ws + 3200000);       // 50001 (pad 50008)
  int*   deg     = row_ptr + 50008;            // 50000 (pad 50048)
  int*   cursor  = deg + 50048;                // 50000 (pad 50048)
  int*   bsum    = cursor + 50048;             // 256
  int*   adj     = bsum + 256;                 // 800000
  float* SUMS    = (float*)(adj + 800000);     // 4096
  float* CNT     = SUMS + 4096;                // 128

  const int kan_blocks  = (N_NODES + 63) / 64;       // 782
  const int edge_blocks = (N_EDGES + 255) / 256;     // 3125
  const int gath_blocks = (N_NODES * 32) / 256;      // 6250

  const int WCONV_STRIDE = 2 * HIDDEN * HIDDEN * GRID_SZ;  // 8192

  // --- CSR build (multi-block scan; every kernel chip-wide)
  zero_int_kernel<<<SCAN_BLOCKS, 256, 0, stream>>>(deg, N_NODES);
  hist_kernel<<<edge_blocks, 256, 0, stream>>>(dst, deg);
  scanA_kernel<<<SCAN_BLOCKS, 256, 0, stream>>>(deg, bsum);
  scanB_kernel<<<1, 256, 0, stream>>>(bsum, row_ptr);
  scanC_kernel<<<SCAN_BLOCKS, 256, 0, stream>>>(deg, bsum, row_ptr, cursor);
  fill_kernel<<<edge_blocks, 256, 0, stream>>>(src, dst, cursor, adj);

  // --- input KAN projection: H = KAN_in(x)
  kan_input_v7<<<kan_blocks, 256, 0, stream>>>(x, W_in, H);

  // --- layer 0: T = KAN_0(H); H = leaky(H + gather(T))
  kan_node_v7<<<kan_blocks, 256, 0, stream>>>(H, W_conv, T);
  gather_update_kernel<<<gath_blocks, 256, 0, stream>>>(T, row_ptr, adj, H);

  // --- layer 1
  kan_node_v7<<<kan_blocks, 256, 0, stream>>>(H, W_conv + WCONV_STRIDE, T);
  gather_update_kernel<<<gath_blocks, 256, 0, stream>>>(T, row_ptr, adj, H);

  // --- pool + readout
  zero_kernel<<<17, 256, 0, stream>>>(SUMS, N_GRAPHS * HIDDEN + N_GRAPHS);
  pool_rl<<<POOL_RANGES / 8, 256, 0, stream>>>(H, batch, SUMS, CNT);
  readout_kernel<<<1, 128, 0, stream>>>(SUMS, CNT, W_out, b_out, out);
}